// Round 1
// 6048.073 us; speedup vs baseline: 1.7928x; 1.7928x over previous
//
#include <hip/hip_runtime.h>
#include <hip/hip_bf16.h>

#define SEQ  2048
#define EDIM 300
#define HDIM 150
#define FH   600   // 4*H
#define DDIM 300   // 2*H
#define DE   600   // D + E

__device__ __forceinline__ float frcp_(float x) { return __builtin_amdgcn_rcpf(x); }
__device__ __forceinline__ float sigm_(float x) { return frcp_(1.f + __expf(-x)); }
__device__ __forceinline__ float tanh_(float x) { return 1.f - 2.f * frcp_(1.f + __expf(2.f * x)); }

__device__ __forceinline__ float wave_red(float v) {
#pragma unroll
    for (int off = 32; off; off >>= 1) v += __shfl_down(v, off, 64);
    return v;
}

__device__ __forceinline__ float rl_(float v, int l) {
    return __uint_as_float((unsigned)__builtin_amdgcn_readlane(__float_as_uint(v), l));
}

// ---------------------------------------------------------------------------
// xp = gather(emb, sentence) @ W{f,b} + b{f,b}   -> [SEQ,600] per direction
// ---------------------------------------------------------------------------
__global__ __launch_bounds__(256) void k_xp(
    const int* __restrict__ sent, const float* __restrict__ emb,
    const float* __restrict__ Wf, const float* __restrict__ bfv,
    const float* __restrict__ Wb, const float* __restrict__ bbv,
    float* __restrict__ xpf, float* __restrict__ xpb)
{
    __shared__ float xs[16][EDIM];
    const int tid = threadIdx.x;
    const int t0  = blockIdx.x * 16;

    for (int i = tid; i < 16 * EDIM; i += 256) {
        int r = i / EDIM, e = i - r * EDIM;
        int row = sent[t0 + r];
        xs[r][e] = emb[(size_t)row * EDIM + e];
    }
    __syncthreads();

    float acc[5][16];
#pragma unroll
    for (int c = 0; c < 5; c++)
#pragma unroll
        for (int r = 0; r < 16; r++) acc[c][r] = 0.f;

    const float* wp[5];
    bool val[5];
#pragma unroll
    for (int c = 0; c < 5; c++) {
        int j = tid + 256 * c;
        val[c] = (j < 1200);
        wp[c] = (j < 600) ? (Wf + j) : (Wb + (j < 1200 ? j - 600 : 0));
    }

    for (int e = 0; e < EDIM; e++) {
        float xr[16];
#pragma unroll
        for (int r = 0; r < 16; r++) xr[r] = xs[r][e];
#pragma unroll
        for (int c = 0; c < 5; c++) {
            if (val[c]) {
                float w = wp[c][(size_t)e * FH];
#pragma unroll
                for (int r = 0; r < 16; r++) acc[c][r] += xr[r] * w;
            }
        }
    }

#pragma unroll
    for (int c = 0; c < 5; c++) {
        int j = tid + 256 * c;
        if (j < 1200) {
            bool isF = (j < 600);
            int jj = isF ? j : j - 600;
            float bias = isF ? bfv[jj] : bbv[jj];
            float* dst = isF ? xpf : xpb;
#pragma unroll
            for (int r = 0; r < 16; r++)
                dst[(size_t)(t0 + r) * FH + jj] = acc[c][r] + bias;
        }
    }
}

// ---------------------------------------------------------------------------
// Serial LSTM recurrence. Block 0 = forward, block 1 = backward.
//
// 256 threads = 4 waves = exactly 1 wave/SIMD (launch_bounds(256,1) -> full
// 512-VGPR budget). Each thread owns columns {tid, tid+256, tid+512<600}
// with the U columns held fully in registers (450 fp32).
//
// h (150 values) is REPLICATED PER WAVE in registers:
//   slot0 = h[lane], slot1 = h[64+lane], slot2 = h[128+lane] (lane<22).
// The z-dot broadcasts h via v_readlane (VALU pipe) -> zero LDS traffic for h.
// Gates are computed redundantly by every wave (each wave updates its own
// h/c register copy), so the only cross-wave dependency per step is zsh.
// zsh is double-buffered -> exactly ONE barrier per step, and the barrier is
// raw s_barrier with an lgkmcnt-only drain (no vmcnt(0) drain: the xp
// prefetch and the hs stores stay in flight across it).
// ---------------------------------------------------------------------------
__global__ __launch_bounds__(256, 1) void k_lstm(
    const float* __restrict__ Uf, const float* __restrict__ Ub,
    const float* __restrict__ xpf, const float* __restrict__ xpb,
    float* __restrict__ hs)
{
    const int dir = blockIdx.x;
    const float* __restrict__ U  = dir ? Ub : Uf;
    const float* __restrict__ xp = dir ? xpb : xpf;

    // double-buffered z; padded to 768 so the c2 write (tid+512 up to 767)
    // never goes OOB for the 168 threads whose 3rd column is invalid.
    __shared__ float zsh[2][768];

    const int tid  = threadIdx.x;
    const int lane = tid & 63;
    const int wv   = tid >> 6;

    const int c0 = tid, c1 = tid + 256, c2 = tid + 512;
    const bool has3 = (c2 < FH);

    // U columns in registers: 3 x 150 fp32
    float U0[150], U1[150], U2[150];
#pragma unroll
    for (int k = 0; k < 150; k++) {
        const float* row = U + (size_t)k * FH;
        U0[k] = row[c0];
        U1[k] = row[c1];
        U2[k] = has3 ? row[c2] : 0.f;
    }

    // per-wave replicated hidden + cell state (registers)
    float h0 = 0.f, h1 = 0.f, h2 = 0.f;
    float cc0 = 0.f, cc1 = 0.f, cc2 = 0.f;

    // prefetch xp for the first step
    {
        const int tt = dir ? (SEQ - 1) : 0;
        const float* xrow = xp + (size_t)tt * FH;
        // (loads issued here; compiler waits before first use)
    }
    const float* xrow0 = xp + (size_t)(dir ? (SEQ - 1) : 0) * FH;
    float xq0 = xrow0[c0];
    float xq1 = xrow0[c1];
    float xq2 = has3 ? xrow0[c2] : 0.f;

    for (int step = 0; step < SEQ; step++) {
        const int t = dir ? (SEQ - 1 - step) : step;
        const int p = step & 1;

        // ---- z-phase: s_c = xp[t][c] + sum_k h[k] * U[k][c] ----
        float s0 = xq0, s1 = xq1, s2 = xq2;
#pragma unroll
        for (int k = 0; k < 64; ++k) {
            const float hk = rl_(h0, k);
            s0 = fmaf(hk, U0[k], s0);
            s1 = fmaf(hk, U1[k], s1);
            s2 = fmaf(hk, U2[k], s2);
        }
#pragma unroll
        for (int k = 0; k < 64; ++k) {
            const float hk = rl_(h1, k);
            s0 = fmaf(hk, U0[64 + k], s0);
            s1 = fmaf(hk, U1[64 + k], s1);
            s2 = fmaf(hk, U2[64 + k], s2);
        }
#pragma unroll
        for (int k = 0; k < 22; ++k) {
            const float hk = rl_(h2, k);
            s0 = fmaf(hk, U0[128 + k], s0);
            s1 = fmaf(hk, U1[128 + k], s1);
            s2 = fmaf(hk, U2[128 + k], s2);
        }

        zsh[p][c0] = s0;
        zsh[p][c1] = s1;
        zsh[p][c2] = s2;   // padded buffer: safe even when !has3

        // prefetch next step's xp while this step finishes (stays in flight
        // across the barrier -- no vmcnt drain below)
        if (step + 1 < SEQ) {
            const int tn = dir ? (SEQ - 2 - step) : (step + 1);
            const float* xrow = xp + (size_t)tn * FH;
            xq0 = xrow[c0];
            xq1 = xrow[c1];
            if (has3) xq2 = xrow[c2];
        }

        // lgkm-only drain + raw barrier (zsh visible; vmcnt NOT drained)
        asm volatile("s_waitcnt lgkmcnt(0)" ::: "memory");
        __builtin_amdgcn_sched_barrier(0);
        __builtin_amdgcn_s_barrier();
        __builtin_amdgcn_sched_barrier(0);

        // ---- gate phase, replicated per wave ----
        {
            const int j = lane;                 // h index lane (0..63)
            float zi = zsh[p][j], zf = zsh[p][HDIM + j];
            float zg = zsh[p][2 * HDIM + j], zo = zsh[p][3 * HDIM + j];
            float ig = sigm_(zi), fg = sigm_(zf), og = sigm_(zo);
            float gg = tanh_(zg);
            cc0 = fg * cc0 + ig * gg;
            h0  = og * tanh_(cc0);
        }
        {
            const int j = 64 + lane;            // h index 64..127
            float zi = zsh[p][j], zf = zsh[p][HDIM + j];
            float zg = zsh[p][2 * HDIM + j], zo = zsh[p][3 * HDIM + j];
            float ig = sigm_(zi), fg = sigm_(zf), og = sigm_(zo);
            float gg = tanh_(zg);
            cc1 = fg * cc1 + ig * gg;
            h1  = og * tanh_(cc1);
        }
        if (lane < 22) {
            const int j = 128 + lane;           // h index 128..149
            float zi = zsh[p][j], zf = zsh[p][HDIM + j];
            float zg = zsh[p][2 * HDIM + j], zo = zsh[p][3 * HDIM + j];
            float ig = sigm_(zi), fg = sigm_(zf), og = sigm_(zo);
            float gg = tanh_(zg);
            cc2 = fg * cc2 + ig * gg;
            h2  = og * tanh_(cc2);
        }

        // one wave writes h(t) to global (fire-and-forget; no drain needed)
        if (wv == 0) {
            float* dst = hs + (size_t)t * DDIM + dir * HDIM;
            dst[lane]      = h0;
            dst[64 + lane] = h1;
            if (lane < 22) dst[128 + lane] = h2;
        }
    }
}

// ---------------------------------------------------------------------------
// out_e = hs @ W_pe + b_pe ; out_s = hs @ W_ps + b_ps
// ---------------------------------------------------------------------------
__global__ __launch_bounds__(256) void k_out(
    const float* __restrict__ hs,
    const float* __restrict__ Wpe, const float* __restrict__ bpe,
    const float* __restrict__ Wps, const float* __restrict__ bps,
    float* __restrict__ oe, float* __restrict__ os)
{
    __shared__ float xs[16 * DDIM];
    const int tid = threadIdx.x;
    const int t0  = blockIdx.x * 16;

    for (int i = tid; i < 16 * DDIM; i += 256) xs[i] = hs[(size_t)t0 * DDIM + i];
    __syncthreads();

    float acc[3][16];
#pragma unroll
    for (int c = 0; c < 3; c++)
#pragma unroll
        for (int r = 0; r < 16; r++) acc[c][r] = 0.f;

    const float* wp[3];
    bool val[3];
#pragma unroll
    for (int c = 0; c < 3; c++) {
        int j = tid + 256 * c;
        val[c] = (j < 600);
        wp[c] = (j < 300) ? (Wpe + j) : (Wps + (j < 600 ? j - 300 : 0));
    }

    for (int e = 0; e < DDIM; e++) {
        float xr[16];
#pragma unroll
        for (int r = 0; r < 16; r++) xr[r] = xs[r * DDIM + e];
#pragma unroll
        for (int c = 0; c < 3; c++) {
            if (val[c]) {
                float w = wp[c][(size_t)e * DDIM];
#pragma unroll
                for (int r = 0; r < 16; r++) acc[c][r] += xr[r] * w;
            }
        }
    }

#pragma unroll
    for (int c = 0; c < 3; c++) {
        int j = tid + 256 * c;
        if (j < 600) {
            bool isE = (j < 300);
            int jj = isE ? j : j - 300;
            float bias = isE ? bpe[jj] : bps[jj];
            float* dst = isE ? oe : os;
#pragma unroll
            for (int r = 0; r < 16; r++)
                dst[(size_t)(t0 + r) * DDIM + jj] = acc[c][r] + bias;
        }
    }
}

// ---------------------------------------------------------------------------
// Primary + secondary attention, accumulate H_HAT / H_BAR (8 sentences/block)
// ---------------------------------------------------------------------------
__global__ __launch_bounds__(256) void k_attn(
    const int* __restrict__ sent, const int* __restrict__ syn,
    const float* __restrict__ emb,
    const float* __restrict__ hs, const float* __restrict__ oeA, const float* __restrict__ osA,
    const float* __restrict__ w_se, const float* __restrict__ b_se,
    const float* __restrict__ w_ss, const float* __restrict__ b_ss,
    float* __restrict__ accHat, float* __restrict__ accBar)
{
    __shared__ float Loe[DDIM], Los[DDIM], Lh[DDIM];
    __shared__ float Lsyn[4][EDIM];
    __shared__ float Lme[EDIM], Lms[EDIM];
    __shared__ float Lred[4][8];
    __shared__ float Latt[8];
    __shared__ float Lco[2];

    const int tid = threadIdx.x;
    const int wv = tid >> 6, lane = tid & 63;
    float aH[3] = {0.f, 0.f, 0.f}, aB[3] = {0.f, 0.f, 0.f};

    for (int i8 = 0; i8 < 8; i8++) {
        const int s = blockIdx.x * 8 + i8;
        for (int i = tid; i < DDIM; i += 256) {
            Loe[i] = oeA[(size_t)s * DDIM + i];
            Los[i] = osA[(size_t)s * DDIM + i];
            Lh[i]  = hs [(size_t)s * DDIM + i];
        }
        const int sid = sent[s];
        for (int i = tid; i < 4 * EDIM; i += 256) {
            int k4 = i / EDIM, e = i - k4 * EDIM;
            int row = syn[sid * 4 + k4];
            Lsyn[k4][e] = emb[(size_t)row * EDIM + e];
        }
        __syncthreads();

        float p[8];
#pragma unroll
        for (int q = 0; q < 8; q++) p[q] = 0.f;
        for (int d = tid; d < EDIM; d += 256) {
            float voe = Loe[d], vos = Los[d];
#pragma unroll
            for (int k4 = 0; k4 < 4; k4++) {
                float sv = Lsyn[k4][d];
                p[k4]     += voe * sv;
                p[4 + k4] += vos * sv;
            }
        }
#pragma unroll
        for (int q = 0; q < 8; q++) {
            float r = wave_red(p[q]);
            if (lane == 0) Lred[wv][q] = r;
        }
        __syncthreads();
        if (tid < 8)
            Latt[tid] = __expf(Lred[0][tid] + Lred[1][tid] + Lred[2][tid] + Lred[3][tid]);
        __syncthreads();

        for (int d = tid; d < EDIM; d += 256) {
            float me = 0.f, ms = 0.f;
#pragma unroll
            for (int k4 = 0; k4 < 4; k4++) {
                float sv = Lsyn[k4][d];
                me += Latt[k4] * sv;
                ms += Latt[4 + k4] * sv;
            }
            Lme[d] = me; Lms[d] = ms;
        }
        __syncthreads();

        float pe = 0.f, ps = 0.f;
        for (int d = tid; d < DE; d += 256) {
            float ve = (d < DDIM) ? Lh[d] : Lme[d - DDIM];
            float vs = (d < DDIM) ? Lh[d] : Lms[d - DDIM];
            pe += ve * w_se[d];
            ps += vs * w_ss[d];
        }
        pe = wave_red(pe); ps = wave_red(ps);
        if (lane == 0) { Lred[wv][0] = pe; Lred[wv][1] = ps; }
        __syncthreads();
        if (tid == 0) {
            float de_ = Lred[0][0] + Lred[1][0] + Lred[2][0] + Lred[3][0];
            float ds_ = Lred[0][1] + Lred[1][1] + Lred[2][1] + Lred[3][1];
            Lco[0] = __expf(tanh_(de_ + b_se[0]));
            Lco[1] = __expf(tanh_(ds_ + b_ss[0]));
        }
        __syncthreads();
        float ce = Lco[0], cs = Lco[1];
#pragma unroll
        for (int cc = 0; cc < 3; cc++) {
            int d = tid + 256 * cc;
            if (d < DE) {
                float ve = (d < DDIM) ? Lh[d] : Lme[d - DDIM];
                float vs = (d < DDIM) ? Lh[d] : Lms[d - DDIM];
                aB[cc] += ce * ve;
                aH[cc] += cs * vs;
            }
        }
        __syncthreads();
    }

#pragma unroll
    for (int cc = 0; cc < 3; cc++) {
        int d = tid + 256 * cc;
        if (d < DE) {
            atomicAdd(&accHat[d], aH[cc]);
            atomicAdd(&accBar[d], aB[cc]);
        }
    }
}

// ---------------------------------------------------------------------------
// Final logits: emotion = H_BAR @ W_eo + b_eo ; sentiment = H_HAT @ W_so + b_so
// ---------------------------------------------------------------------------
__global__ __launch_bounds__(64) void k_final(
    const float* __restrict__ accHat, const float* __restrict__ accBar,
    const float* __restrict__ W_eo, const float* __restrict__ b_eo,
    const float* __restrict__ W_so, const float* __restrict__ b_so,
    float* __restrict__ out)
{
    const int lane = threadIdx.x;
#pragma unroll
    for (int jq = 0; jq < 8; jq++) {
        float pp = 0.f;
        for (int d = lane; d < DE; d += 64) pp += accBar[d] * W_eo[d * 8 + jq];
        pp = wave_red(pp);
        if (lane == 0) out[jq] = pp + b_eo[jq];
    }
    float pp = 0.f;
    for (int d = lane; d < DE; d += 64) pp += accHat[d] * W_so[d];
    pp = wave_red(pp);
    if (lane == 0) out[8] = pp + b_so[0];
}

extern "C" void kernel_launch(void* const* d_in, const int* in_sizes, int n_in,
                              void* d_out, int out_size, void* d_ws, size_t ws_size,
                              hipStream_t stream)
{
    const int*   sent = (const int*)  d_in[0];
    const float* emb  = (const float*)d_in[1];
    const int*   syn  = (const int*)  d_in[2];
    const float* Wf   = (const float*)d_in[3];
    const float* Uf   = (const float*)d_in[4];
    const float* bfv  = (const float*)d_in[5];
    const float* Wb   = (const float*)d_in[6];
    const float* Ub   = (const float*)d_in[7];
    const float* bbv  = (const float*)d_in[8];
    const float* Wpe  = (const float*)d_in[9];
    const float* bpe  = (const float*)d_in[10];
    const float* Wps  = (const float*)d_in[11];
    const float* bps  = (const float*)d_in[12];
    const float* wse  = (const float*)d_in[13];
    const float* bse  = (const float*)d_in[14];
    const float* wss  = (const float*)d_in[15];
    const float* bss  = (const float*)d_in[16];
    const float* Weo  = (const float*)d_in[17];
    const float* beo  = (const float*)d_in[18];
    const float* Wso  = (const float*)d_in[19];
    const float* bso  = (const float*)d_in[20];

    float* ws  = (float*)d_ws;
    float* xpf = ws;
    float* xpb = xpf + (size_t)SEQ * FH;
    float* hsA = xpb + (size_t)SEQ * FH;
    float* oeA = hsA + (size_t)SEQ * DDIM;
    float* osA = oeA + (size_t)SEQ * DDIM;
    float* accHat = osA + (size_t)SEQ * DDIM;
    float* accBar = accHat + DE;

    hipMemsetAsync(accHat, 0, 2 * DE * sizeof(float), stream);

    k_xp  <<<SEQ / 16, 256, 0, stream>>>(sent, emb, Wf, bfv, Wb, bbv, xpf, xpb);
    k_lstm<<<2,        256, 0, stream>>>(Uf, Ub, xpf, xpb, hsA);
    k_out <<<SEQ / 16, 256, 0, stream>>>(hsA, Wpe, bpe, Wps, bps, oeA, osA);
    k_attn<<<SEQ / 8,  256, 0, stream>>>(sent, syn, emb, hsA, oeA, osA,
                                         wse, bse, wss, bss, accHat, accBar);
    k_final<<<1,        64, 0, stream>>>(accHat, accBar, Weo, beo, Wso, bso,
                                         (float*)d_out);
}

// Round 3
// 3626.737 us; speedup vs baseline: 2.9898x; 1.6676x over previous
//
#include <hip/hip_runtime.h>
#include <hip/hip_bf16.h>

#define SEQ  2048
#define EDIM 300
#define HDIM 150
#define FH   600   // 4*H
#define DDIM 300   // 2*H
#define DE   600   // D + E

__device__ __forceinline__ float frcp_(float x) { return __builtin_amdgcn_rcpf(x); }
__device__ __forceinline__ float sigm_(float x) { return frcp_(1.f + __expf(-x)); }
__device__ __forceinline__ float tanh_(float x) { return 1.f - 2.f * frcp_(1.f + __expf(2.f * x)); }

__device__ __forceinline__ float wave_red(float v) {
#pragma unroll
    for (int off = 32; off; off >>= 1) v += __shfl_down(v, off, 64);
    return v;
}

__device__ __forceinline__ float rl_(float v, int l) {
    return __uint_as_float((unsigned)__builtin_amdgcn_readlane(__float_as_uint(v), l));
}

// ---------------------------------------------------------------------------
// xp = gather(emb, sentence) @ W{f,b} + b{f,b}   -> [SEQ,600] per direction
// ---------------------------------------------------------------------------
__global__ __launch_bounds__(256) void k_xp(
    const int* __restrict__ sent, const float* __restrict__ emb,
    const float* __restrict__ Wf, const float* __restrict__ bfv,
    const float* __restrict__ Wb, const float* __restrict__ bbv,
    float* __restrict__ xpf, float* __restrict__ xpb)
{
    __shared__ float xs[16][EDIM];
    const int tid = threadIdx.x;
    const int t0  = blockIdx.x * 16;

    for (int i = tid; i < 16 * EDIM; i += 256) {
        int r = i / EDIM, e = i - r * EDIM;
        int row = sent[t0 + r];
        xs[r][e] = emb[(size_t)row * EDIM + e];
    }
    __syncthreads();

    float acc[5][16];
#pragma unroll
    for (int c = 0; c < 5; c++)
#pragma unroll
        for (int r = 0; r < 16; r++) acc[c][r] = 0.f;

    const float* wp[5];
    bool val[5];
#pragma unroll
    for (int c = 0; c < 5; c++) {
        int j = tid + 256 * c;
        val[c] = (j < 1200);
        wp[c] = (j < 600) ? (Wf + j) : (Wb + (j < 1200 ? j - 600 : 0));
    }

    for (int e = 0; e < EDIM; e++) {
        float xr[16];
#pragma unroll
        for (int r = 0; r < 16; r++) xr[r] = xs[r][e];
#pragma unroll
        for (int c = 0; c < 5; c++) {
            if (val[c]) {
                float w = wp[c][(size_t)e * FH];
#pragma unroll
                for (int r = 0; r < 16; r++) acc[c][r] += xr[r] * w;
            }
        }
    }

#pragma unroll
    for (int c = 0; c < 5; c++) {
        int j = tid + 256 * c;
        if (j < 1200) {
            bool isF = (j < 600);
            int jj = isF ? j : j - 600;
            float bias = isF ? bfv[jj] : bbv[jj];
            float* dst = isF ? xpf : xpb;
#pragma unroll
            for (int r = 0; r < 16; r++)
                dst[(size_t)(t0 + r) * FH + jj] = acc[c][r] + bias;
        }
    }
}

// ---------------------------------------------------------------------------
// Serial LSTM recurrence. Block 0 = forward, block 1 = backward.
//
// Round-3 structure (fixes round-2's missing-column bug):
//   512 threads = 8 waves = 2 waves/SIMD (launch_bounds(512,2) -> 256 VGPRs).
//   Wave wv = (kg = wv&3, cg = wv>>2):
//     kg owns k-slice [38kg, 38kg+38)  (rows >=150 zero-padded)
//     cg owns column half [300cg, 300cg+300)
//   Lane covers 5 columns: col_g = 300cg + 64g + lane (g=4 valid iff lane<44).
//   U slice per thread = 38x5 = 190 fp32 -> pure VGPR, no AGPR spill.
//   zpart[p][kg][col] now gets EVERY column: the two cg-replicas of a kg
//   write disjoint halves. Gate j sums the 4 kg-partials (16 ds_read_b32).
//   h[38kg+lane], c[38kg+lane] live in lane regs of both cg-replicas (gates
//   computed redundantly), so z-phase readlanes are wave-local (38/wave).
//   Double-buffered zpart, ONE raw s_barrier per step, lgkm-only drain
//   (xp prefetch + hs stores stay in flight across the barrier).
// ---------------------------------------------------------------------------
__global__ __launch_bounds__(512, 2) void k_lstm(
    const float* __restrict__ Uf, const float* __restrict__ Ub,
    const float* __restrict__ xpf, const float* __restrict__ xpb,
    float* __restrict__ hs)
{
    const int dir = blockIdx.x;
    const float* __restrict__ U  = dir ? Ub : Uf;
    const float* __restrict__ xp = dir ? xpb : xpf;

    __shared__ float zpart[2][4][FH];      // [dbuf][kg][col] = 19.2 KiB

    const int tid  = threadIdx.x;
    const int lane = tid & 63;
    const int wv   = tid >> 6;             // 0..7
    const int kg   = wv & 3;               // k-group
    const int cg   = wv >> 2;              // column-half group
    const int kw0  = kg * 38;

    // 5 columns per lane (5th valid only for lane<44); clamp for loads.
    const bool has5 = (lane < 44);
    int col[5];
#pragma unroll
    for (int g = 0; g < 5; g++) {
        int c = 300 * cg + 64 * g + lane;
        col[g] = (g == 4 && !has5) ? (300 * cg + 299) : c;
    }

    // U k-slice for my 5 columns: 190 fp32 in VGPRs
    float Ur[5][38];
#pragma unroll
    for (int kk = 0; kk < 38; kk++) {
        const int k   = kw0 + kk;
        const bool kv = (k < HDIM);
        const float* row = U + (size_t)(kv ? k : 0) * FH;
        const float m = kv ? 1.f : 0.f;
#pragma unroll
        for (int g = 0; g < 5; g++)
            Ur[g][kk] = m * row[col[g]];
    }

    // distributed hidden/cell state: lane l owns h[kw0+l] (both cg-replicas)
    const int j  = kw0 + lane;
    const bool gv = (lane < 38) && (j < HDIM);
    float hreg = 0.f, creg = 0.f;

    // xp prefetch for the first step (gate lanes only)
    float xq0 = 0.f, xq1 = 0.f, xq2 = 0.f, xq3 = 0.f;
    if (gv) {
        const float* xrow = xp + (size_t)(dir ? (SEQ - 1) : 0) * FH;
        xq0 = xrow[j];
        xq1 = xrow[HDIM + j];
        xq2 = xrow[2 * HDIM + j];
        xq3 = xrow[3 * HDIM + j];
    }

    for (int step = 0; step < SEQ; step++) {
        const int t = dir ? (SEQ - 1 - step) : step;
        const int p = step & 1;

        // ---- z-phase: partial_kg[col] = sum_{k in slice} h[k] * U[k][col] ----
        float s0 = 0.f, s1 = 0.f, s2 = 0.f, s3 = 0.f, s4 = 0.f;
#pragma unroll
        for (int kk = 0; kk < 38; kk++) {
            const float hk = rl_(hreg, kk);    // wave-local broadcast
            s0 = fmaf(hk, Ur[0][kk], s0);
            s1 = fmaf(hk, Ur[1][kk], s1);
            s2 = fmaf(hk, Ur[2][kk], s2);
            s3 = fmaf(hk, Ur[3][kk], s3);
            s4 = fmaf(hk, Ur[4][kk], s4);
        }
        zpart[p][kg][col[0]] = s0;
        zpart[p][kg][col[1]] = s1;
        zpart[p][kg][col[2]] = s2;
        zpart[p][kg][col[3]] = s3;
        if (has5) zpart[p][kg][col[4]] = s4;

        // lgkm-only drain + raw barrier (vmcnt stays in flight)
        asm volatile("s_waitcnt lgkmcnt(0)" ::: "memory");
        __builtin_amdgcn_sched_barrier(0);
        __builtin_amdgcn_s_barrier();
        __builtin_amdgcn_sched_barrier(0);

        // ---- gate phase: lanes 0..37 own h[kw0+lane]; replicated in cg ----
        if (gv) {
            float z0 = xq0, z1 = xq1, z2 = xq2, z3 = xq3;
#pragma unroll
            for (int k4 = 0; k4 < 4; k4++) {
                z0 += zpart[p][k4][j];
                z1 += zpart[p][k4][HDIM + j];
                z2 += zpart[p][k4][2 * HDIM + j];
                z3 += zpart[p][k4][3 * HDIM + j];
            }

            // prefetch next step's xp while the gate chain runs
            if (step + 1 < SEQ) {
                const int tn = dir ? (SEQ - 2 - step) : (step + 1);
                const float* xrow = xp + (size_t)tn * FH;
                xq0 = xrow[j];
                xq1 = xrow[HDIM + j];
                xq2 = xrow[2 * HDIM + j];
                xq3 = xrow[3 * HDIM + j];
            }

            const float ig = sigm_(z0);
            const float fg = sigm_(z1);
            const float gg = tanh_(z2);
            const float og = sigm_(z3);
            creg = fg * creg + ig * gg;
            hreg = og * tanh_(creg);

            if (cg == 0)
                hs[(size_t)t * DDIM + dir * HDIM + j] = hreg;  // fire-and-forget
        }
    }
}

// ---------------------------------------------------------------------------
// out_e = hs @ W_pe + b_pe ; out_s = hs @ W_ps + b_ps
// ---------------------------------------------------------------------------
__global__ __launch_bounds__(256) void k_out(
    const float* __restrict__ hs,
    const float* __restrict__ Wpe, const float* __restrict__ bpe,
    const float* __restrict__ Wps, const float* __restrict__ bps,
    float* __restrict__ oe, float* __restrict__ os)
{
    __shared__ float xs[16 * DDIM];
    const int tid = threadIdx.x;
    const int t0  = blockIdx.x * 16;

    for (int i = tid; i < 16 * DDIM; i += 256) xs[i] = hs[(size_t)t0 * DDIM + i];
    __syncthreads();

    float acc[3][16];
#pragma unroll
    for (int c = 0; c < 3; c++)
#pragma unroll
        for (int r = 0; r < 16; r++) acc[c][r] = 0.f;

    const float* wp[3];
    bool val[3];
#pragma unroll
    for (int c = 0; c < 3; c++) {
        int j = tid + 256 * c;
        val[c] = (j < 600);
        wp[c] = (j < 300) ? (Wpe + j) : (Wps + (j < 600 ? j - 300 : 0));
    }

    for (int e = 0; e < DDIM; e++) {
        float xr[16];
#pragma unroll
        for (int r = 0; r < 16; r++) xr[r] = xs[r * DDIM + e];
#pragma unroll
        for (int c = 0; c < 3; c++) {
            if (val[c]) {
                float w = wp[c][(size_t)e * DDIM];
#pragma unroll
                for (int r = 0; r < 16; r++) acc[c][r] += xr[r] * w;
            }
        }
    }

#pragma unroll
    for (int c = 0; c < 3; c++) {
        int j = tid + 256 * c;
        if (j < 600) {
            bool isE = (j < 300);
            int jj = isE ? j : j - 300;
            float bias = isE ? bpe[jj] : bps[jj];
            float* dst = isE ? oe : os;
#pragma unroll
            for (int r = 0; r < 16; r++)
                dst[(size_t)(t0 + r) * DDIM + jj] = acc[c][r] + bias;
        }
    }
}

// ---------------------------------------------------------------------------
// Primary + secondary attention, accumulate H_HAT / H_BAR (8 sentences/block)
// ---------------------------------------------------------------------------
__global__ __launch_bounds__(256) void k_attn(
    const int* __restrict__ sent, const int* __restrict__ syn,
    const float* __restrict__ emb,
    const float* __restrict__ hs, const float* __restrict__ oeA, const float* __restrict__ osA,
    const float* __restrict__ w_se, const float* __restrict__ b_se,
    const float* __restrict__ w_ss, const float* __restrict__ b_ss,
    float* __restrict__ accHat, float* __restrict__ accBar)
{
    __shared__ float Loe[DDIM], Los[DDIM], Lh[DDIM];
    __shared__ float Lsyn[4][EDIM];
    __shared__ float Lme[EDIM], Lms[EDIM];
    __shared__ float Lred[4][8];
    __shared__ float Latt[8];
    __shared__ float Lco[2];

    const int tid = threadIdx.x;
    const int wv = tid >> 6, lane = tid & 63;
    float aH[3] = {0.f, 0.f, 0.f}, aB[3] = {0.f, 0.f, 0.f};

    for (int i8 = 0; i8 < 8; i8++) {
        const int s = blockIdx.x * 8 + i8;
        for (int i = tid; i < DDIM; i += 256) {
            Loe[i] = oeA[(size_t)s * DDIM + i];
            Los[i] = osA[(size_t)s * DDIM + i];
            Lh[i]  = hs [(size_t)s * DDIM + i];
        }
        const int sid = sent[s];
        for (int i = tid; i < 4 * EDIM; i += 256) {
            int k4 = i / EDIM, e = i - k4 * EDIM;
            int row = syn[sid * 4 + k4];
            Lsyn[k4][e] = emb[(size_t)row * EDIM + e];
        }
        __syncthreads();

        float p[8];
#pragma unroll
        for (int q = 0; q < 8; q++) p[q] = 0.f;
        for (int d = tid; d < EDIM; d += 256) {
            float voe = Loe[d], vos = Los[d];
#pragma unroll
            for (int k4 = 0; k4 < 4; k4++) {
                float sv = Lsyn[k4][d];
                p[k4]     += voe * sv;
                p[4 + k4] += vos * sv;
            }
        }
#pragma unroll
        for (int q = 0; q < 8; q++) {
            float r = wave_red(p[q]);
            if (lane == 0) Lred[wv][q] = r;
        }
        __syncthreads();
        if (tid < 8)
            Latt[tid] = __expf(Lred[0][tid] + Lred[1][tid] + Lred[2][tid] + Lred[3][tid]);
        __syncthreads();

        for (int d = tid; d < EDIM; d += 256) {
            float me = 0.f, ms = 0.f;
#pragma unroll
            for (int k4 = 0; k4 < 4; k4++) {
                float sv = Lsyn[k4][d];
                me += Latt[k4] * sv;
                ms += Latt[4 + k4] * sv;
            }
            Lme[d] = me; Lms[d] = ms;
        }
        __syncthreads();

        float pe = 0.f, ps = 0.f;
        for (int d = tid; d < DE; d += 256) {
            float ve = (d < DDIM) ? Lh[d] : Lme[d - DDIM];
            float vs = (d < DDIM) ? Lh[d] : Lms[d - DDIM];
            pe += ve * w_se[d];
            ps += vs * w_ss[d];
        }
        pe = wave_red(pe); ps = wave_red(ps);
        if (lane == 0) { Lred[wv][0] = pe; Lred[wv][1] = ps; }
        __syncthreads();
        if (tid == 0) {
            float de_ = Lred[0][0] + Lred[1][0] + Lred[2][0] + Lred[3][0];
            float ds_ = Lred[0][1] + Lred[1][1] + Lred[2][1] + Lred[3][1];
            Lco[0] = __expf(tanh_(de_ + b_se[0]));
            Lco[1] = __expf(tanh_(ds_ + b_ss[0]));
        }
        __syncthreads();
        float ce = Lco[0], cs = Lco[1];
#pragma unroll
        for (int cc = 0; cc < 3; cc++) {
            int d = tid + 256 * cc;
            if (d < DE) {
                float ve = (d < DDIM) ? Lh[d] : Lme[d - DDIM];
                float vs = (d < DDIM) ? Lh[d] : Lms[d - DDIM];
                aB[cc] += ce * ve;
                aH[cc] += cs * vs;
            }
        }
        __syncthreads();
    }

#pragma unroll
    for (int cc = 0; cc < 3; cc++) {
        int d = tid + 256 * cc;
        if (d < DE) {
            atomicAdd(&accHat[d], aH[cc]);
            atomicAdd(&accBar[d], aB[cc]);
        }
    }
}

// ---------------------------------------------------------------------------
// Final logits: emotion = H_BAR @ W_eo + b_eo ; sentiment = H_HAT @ W_so + b_so
// ---------------------------------------------------------------------------
__global__ __launch_bounds__(64) void k_final(
    const float* __restrict__ accHat, const float* __restrict__ accBar,
    const float* __restrict__ W_eo, const float* __restrict__ b_eo,
    const float* __restrict__ W_so, const float* __restrict__ b_so,
    float* __restrict__ out)
{
    const int lane = threadIdx.x;
#pragma unroll
    for (int jq = 0; jq < 8; jq++) {
        float pp = 0.f;
        for (int d = lane; d < DE; d += 64) pp += accBar[d] * W_eo[d * 8 + jq];
        pp = wave_red(pp);
        if (lane == 0) out[jq] = pp + b_eo[jq];
    }
    float pp = 0.f;
    for (int d = lane; d < DE; d += 64) pp += accHat[d] * W_so[d];
    pp = wave_red(pp);
    if (lane == 0) out[8] = pp + b_so[0];
}

extern "C" void kernel_launch(void* const* d_in, const int* in_sizes, int n_in,
                              void* d_out, int out_size, void* d_ws, size_t ws_size,
                              hipStream_t stream)
{
    const int*   sent = (const int*)  d_in[0];
    const float* emb  = (const float*)d_in[1];
    const int*   syn  = (const int*)  d_in[2];
    const float* Wf   = (const float*)d_in[3];
    const float* Uf   = (const float*)d_in[4];
    const float* bfv  = (const float*)d_in[5];
    const float* Wb   = (const float*)d_in[6];
    const float* Ub   = (const float*)d_in[7];
    const float* bbv  = (const float*)d_in[8];
    const float* Wpe  = (const float*)d_in[9];
    const float* bpe  = (const float*)d_in[10];
    const float* Wps  = (const float*)d_in[11];
    const float* bps  = (const float*)d_in[12];
    const float* wse  = (const float*)d_in[13];
    const float* bse  = (const float*)d_in[14];
    const float* wss  = (const float*)d_in[15];
    const float* bss  = (const float*)d_in[16];
    const float* Weo  = (const float*)d_in[17];
    const float* beo  = (const float*)d_in[18];
    const float* Wso  = (const float*)d_in[19];
    const float* bso  = (const float*)d_in[20];

    float* ws  = (float*)d_ws;
    float* xpf = ws;
    float* xpb = xpf + (size_t)SEQ * FH;
    float* hsA = xpb + (size_t)SEQ * FH;
    float* oeA = hsA + (size_t)SEQ * DDIM;
    float* osA = oeA + (size_t)SEQ * DDIM;
    float* accHat = osA + (size_t)SEQ * DDIM;
    float* accBar = accHat + DE;

    hipMemsetAsync(accHat, 0, 2 * DE * sizeof(float), stream);

    k_xp  <<<SEQ / 16, 256, 0, stream>>>(sent, emb, Wf, bfv, Wb, bbv, xpf, xpb);
    k_lstm<<<2,        512, 0, stream>>>(Uf, Ub, xpf, xpb, hsA);
    k_out <<<SEQ / 16, 256, 0, stream>>>(hsA, Wpe, bpe, Wps, bps, oeA, osA);
    k_attn<<<SEQ / 8,  256, 0, stream>>>(sent, syn, emb, hsA, oeA, osA,
                                         wse, bse, wss, bss, accHat, accBar);
    k_final<<<1,        64, 0, stream>>>(accHat, accBar, Weo, beo, Wso, bso,
                                         (float*)d_out);
}